// Round 4
// baseline (1906.937 us; speedup 1.0000x reference)
//
#include <hip/hip_runtime.h>
#include <hip/hip_bf16.h>
#include <stdint.h>

// Capsule routing, f32 in/out. B=32, Nin=2048, Din=16, Nout=64, Dout=32, 3 iters.
// Round 4: register-blocked G=8 (round-2 structure) + bf16 W materialized during
// pass 0 (L3-resident, half the VGPRs -> loads batch) + 2 blocks/CU occupancy.

#define CB    32
#define NIN   2048
#define DIN   16
#define NOUT  64
#define DOUT  32
#define CHUNK 16
#define NCHUNK (NIN / CHUNK)     // 128
#define G     8
#define WI    (NOUT * DOUT * DIN)          // 32768 floats per i
#define WELEM ((size_t)NIN * WI)           // 67,108,864 elements

static __device__ __forceinline__ uint32_t pack_bf2(float a, float b) {
    __hip_bfloat162 h = __float22bfloat162_rn(make_float2(a, b));
    uint32_t u; __builtin_memcpy(&u, &h, 4); return u;
}
static __device__ __forceinline__ float bf_lo(uint32_t u) {
    uint32_t v = u << 16; float f; __builtin_memcpy(&f, &v, 4); return f;
}
static __device__ __forceinline__ float bf_hi(uint32_t u) {
    uint32_t v = u & 0xffff0000u; float f; __builtin_memcpy(&f, &v, 4); return f;
}

// ---------------- Pass 0: uniform coupling, f32 W, emits bf16 W copy ----------------
// 512 thr: j = t>>3, dq = t&7 (d0 = dq*4). Block = (chunk of 16 i, batch-group of 8).
__global__ __launch_bounds__(512, 4) void caps_pass0(
    const float* __restrict__ x, const float* __restrict__ W,
    uint32_t* __restrict__ Wbf, float* __restrict__ s_partial)
{
    const int p     = blockIdx.x;                  // 512 blocks, 2/CU
    const int chunk = (p >> 5) * 8 + (p & 7);      // 4 bg of a chunk share an XCD
    const int bg    = (p & 31) >> 3;
    const int b0    = bg * G;
    const int t     = threadIdx.x;
    const int j     = t >> 3, dq = t & 7;

    __shared__ float sh_x[G * CHUNK * DIN];        // 8KB
    {
        const int bb = t >> 6, rem = t & 63;
        *(float4*)&sh_x[bb * (CHUNK * DIN) + rem * 4] =
            *(const float4*)(x + (size_t)(b0 + bb) * (NIN * DIN)
                               + (size_t)chunk * (CHUNK * DIN) + rem * 4);
    }
    __syncthreads();

    float sacc[G][4];
#pragma unroll
    for (int bb = 0; bb < G; ++bb)
#pragma unroll
        for (int r = 0; r < 4; ++r) sacc[bb][r] = 0.f;

    const size_t thrW = (size_t)j * (DOUT * DIN) + (size_t)(dq * 4) * DIN;

#pragma unroll 1
    for (int ii = 0; ii < CHUNK; ++ii) {
        const int i = chunk * CHUNK + ii;
        const float4* wp = (const float4*)(W + (size_t)i * WI + thrW);
        float4 wf[16];
#pragma unroll
        for (int q = 0; q < 16; ++q) wf[q] = wp[q];

        // emit bf16 W: each i written by exactly one bg (spread the cost)
        if (Wbf != nullptr && bg == (ii & 3)) {
            uint32_t* dst = Wbf + ((size_t)i * WI + thrW) / 2;
#pragma unroll
            for (int g8 = 0; g8 < 8; ++g8) {
                uint4 pk;
                pk.x = pack_bf2(wf[2*g8].x,   wf[2*g8].y);
                pk.y = pack_bf2(wf[2*g8].z,   wf[2*g8].w);
                pk.z = pack_bf2(wf[2*g8+1].x, wf[2*g8+1].y);
                pk.w = pack_bf2(wf[2*g8+1].z, wf[2*g8+1].w);
                *(uint4*)(dst + g8 * 4) = pk;
            }
        }

#pragma unroll
        for (int bb = 0; bb < G; ++bb) {
            const float4* xp = (const float4*)&sh_x[bb * (CHUNK * DIN) + ii * DIN];
            const float4 x0 = xp[0], x1 = xp[1], x2 = xp[2], x3 = xp[3];
#pragma unroll
            for (int r = 0; r < 4; ++r) {
                const float4 wA = wf[r*4+0], wB = wf[r*4+1], wC = wf[r*4+2], wD = wf[r*4+3];
                sacc[bb][r] += wA.x*x0.x + wA.y*x0.y + wA.z*x0.z + wA.w*x0.w
                             + wB.x*x1.x + wB.y*x1.y + wB.z*x1.z + wB.w*x1.w
                             + wC.x*x2.x + wC.y*x2.y + wC.z*x2.z + wC.w*x2.w
                             + wD.x*x3.x + wD.y*x3.y + wD.z*x3.z + wD.w*x3.w;
            }
        }
    }

#pragma unroll
    for (int bb = 0; bb < G; ++bb) {
        float4 o;
        o.x = sacc[bb][0] * (1.0f/64.0f); o.y = sacc[bb][1] * (1.0f/64.0f);
        o.z = sacc[bb][2] * (1.0f/64.0f); o.w = sacc[bb][3] * (1.0f/64.0f);
        *(float4*)(s_partial + ((size_t)(b0 + bb) * NCHUNK + chunk) * (NOUT * DOUT) + t * 4) = o;
    }
}

// ---------------- Passes 1-2: routing iterations ----------------
template <int IT, int WBF>
__global__ __launch_bounds__(512, 4) void caps_pass(
    const float* __restrict__ x, const void* __restrict__ Wv,
    const float* __restrict__ v_prev, const float* __restrict__ blog_in,
    float* __restrict__ blog_out, float* __restrict__ s_partial)
{
    const int p     = blockIdx.x;
    const int chunk = (p >> 5) * 8 + (p & 7);
    const int bg    = (p & 31) >> 3;
    const int b0    = bg * G;
    const int t     = threadIdx.x;
    const int j     = t >> 3, dq = t & 7;
    const int w     = t >> 6, l = t & 63;

    __shared__ float    sh_x[G * CHUNK * DIN];   // 8KB
    __shared__ float    sh_bl[2][G * NOUT];      // 4KB (double-buffered)
    __shared__ float    sh_red[2][G * 2];
    __shared__ uint32_t sh_vp[G * NOUT * DOUT / 2]; // packed-bf16 v slice, 32KB

    {
        const int bb = t >> 6, rem = t & 63;
        *(float4*)&sh_x[bb * (CHUNK * DIN) + rem * 4] =
            *(const float4*)(x + (size_t)(b0 + bb) * (NIN * DIN)
                               + (size_t)chunk * (CHUNK * DIN) + rem * 4);
    }
    for (int q = t; q < G * NOUT * DOUT / 2; q += 512) {
        const float2 vv = *(const float2*)(v_prev + (size_t)b0 * (NOUT * DOUT) + (size_t)q * 2);
        sh_vp[q] = pack_bf2(vv.x, vv.y);
    }
    __syncthreads();

    float sacc[G][4];
#pragma unroll
    for (int bb = 0; bb < G; ++bb)
#pragma unroll
        for (int r = 0; r < 4; ++r) sacc[bb][r] = 0.f;

    const uint32_t* Wb = (const uint32_t*)Wv;
    const float*    Wf = (const float*)Wv;
    const size_t thrW = (size_t)j * (DOUT * DIN) + (size_t)(dq * 4) * DIN;

#pragma unroll 1
    for (int ii = 0; ii < CHUNK; ++ii) {
        const int i = chunk * CHUNK + ii;

        float uh[G][4];
#pragma unroll
        for (int bb = 0; bb < G; ++bb)
#pragma unroll
            for (int r = 0; r < 4; ++r) uh[bb][r] = 0.f;

        if constexpr (WBF) {
            const uint4* wp = (const uint4*)(Wb + ((size_t)i * WI + thrW) / 2);
            uint4 wq[8];
#pragma unroll
            for (int q = 0; q < 8; ++q) wq[q] = wp[q];
#pragma unroll
            for (int kh = 0; kh < 2; ++kh) {
                float wv[4][8];
#pragma unroll
                for (int r = 0; r < 4; ++r) {
                    const uint4 q = wq[r * 2 + kh];
                    wv[r][0] = bf_lo(q.x); wv[r][1] = bf_hi(q.x);
                    wv[r][2] = bf_lo(q.y); wv[r][3] = bf_hi(q.y);
                    wv[r][4] = bf_lo(q.z); wv[r][5] = bf_hi(q.z);
                    wv[r][6] = bf_lo(q.w); wv[r][7] = bf_hi(q.w);
                }
#pragma unroll
                for (int bb = 0; bb < G; ++bb) {
                    const float4* xp = (const float4*)&sh_x[bb * (CHUNK * DIN) + ii * DIN + kh * 8];
                    const float4 xA = xp[0], xB = xp[1];
#pragma unroll
                    for (int r = 0; r < 4; ++r) {
                        uh[bb][r] += wv[r][0]*xA.x + wv[r][1]*xA.y + wv[r][2]*xA.z + wv[r][3]*xA.w
                                   + wv[r][4]*xB.x + wv[r][5]*xB.y + wv[r][6]*xB.z + wv[r][7]*xB.w;
                    }
                }
            }
        } else {
            const float4* wp = (const float4*)(Wf + (size_t)i * WI + thrW);
            float4 wf[16];
#pragma unroll
            for (int q = 0; q < 16; ++q) wf[q] = wp[q];
#pragma unroll
            for (int bb = 0; bb < G; ++bb) {
                const float4* xp = (const float4*)&sh_x[bb * (CHUNK * DIN) + ii * DIN];
                const float4 x0 = xp[0], x1 = xp[1], x2 = xp[2], x3 = xp[3];
#pragma unroll
                for (int r = 0; r < 4; ++r) {
                    const float4 wA = wf[r*4+0], wB = wf[r*4+1], wC = wf[r*4+2], wD = wf[r*4+3];
                    uh[bb][r] += wA.x*x0.x + wA.y*x0.y + wA.z*x0.z + wA.w*x0.w
                               + wB.x*x1.x + wB.y*x1.y + wB.z*x1.z + wB.w*x1.w
                               + wC.x*x2.x + wC.y*x2.y + wC.z*x2.z + wC.w*x2.w
                               + wD.x*x3.x + wD.y*x3.y + wD.z*x3.z + wD.w*x3.w;
                }
            }
        }

        const int par = ii & 1;
        // logits: dot over all 32 d via oct butterfly; store to LDS (+ blog I/O)
#pragma unroll
        for (int bb = 0; bb < G; ++bb) {
            const uint2 vp = *(const uint2*)&sh_vp[bb * (NOUT * DOUT / 2) + j * (DOUT / 2) + dq * 2];
            float dlg = uh[bb][0]*bf_lo(vp.x) + uh[bb][1]*bf_hi(vp.x)
                      + uh[bb][2]*bf_lo(vp.y) + uh[bb][3]*bf_hi(vp.y);
            dlg += __shfl_xor(dlg, 1);
            dlg += __shfl_xor(dlg, 2);
            dlg += __shfl_xor(dlg, 4);
            if (IT == 2) dlg += blog_in[((size_t)(b0 + bb) * NIN + i) * NOUT + j];
            if (dq == 0) {
                sh_bl[par][bb * NOUT + j] = dlg;
                if (IT == 1) blog_out[((size_t)(b0 + bb) * NIN + i) * NOUT + j] = dlg;
            }
        }
        __syncthreads();   // logits visible

        // softmax over 64 j: wave w handles local batch w
        {
            const float val = sh_bl[par][w * NOUT + l];
            float m = val;
#pragma unroll
            for (int o = 32; o; o >>= 1) m = fmaxf(m, __shfl_xor(m, o));
            float e = __expf(val - m);
#pragma unroll
            for (int o = 32; o; o >>= 1) e += __shfl_xor(e, o);
            if (l == 0) { sh_red[par][w * 2] = m; sh_red[par][w * 2 + 1] = 1.0f / e; }
        }
        __syncthreads();   // m, 1/sum visible

#pragma unroll
        for (int bb = 0; bb < G; ++bb) {
            const float m   = sh_red[par][bb * 2];
            const float inv = sh_red[par][bb * 2 + 1];
            const float c = __expf(sh_bl[par][bb * NOUT + j] - m) * inv;
#pragma unroll
            for (int r = 0; r < 4; ++r) sacc[bb][r] += c * uh[bb][r];
        }
    }

#pragma unroll
    for (int bb = 0; bb < G; ++bb) {
        float4 o;
        o.x = sacc[bb][0]; o.y = sacc[bb][1]; o.z = sacc[bb][2]; o.w = sacc[bb][3];
        *(float4*)(s_partial + ((size_t)(b0 + bb) * NCHUNK + chunk) * (NOUT * DOUT) + t * 4) = o;
    }
}

// ---------------- Reduce partials, add bias, squash. One wave per (b,j). ----------------
__global__ __launch_bounds__(64) void caps_squash(
    const float* __restrict__ s_partial,  // [B, NCHUNK, NOUT*DOUT]
    const float* __restrict__ bias,       // [NOUT, DOUT]
    float* __restrict__ v_out)            // [B, NOUT, DOUT]
{
    const int bj = blockIdx.x;
    const int b  = bj / NOUT;
    const int j  = bj % NOUT;
    const int t  = threadIdx.x;
    const int d  = t & 31;
    const int h  = t >> 5;

    float sv = 0.f;
    for (int c = h; c < NCHUNK; c += 2)
        sv += s_partial[((size_t)b * NCHUNK + c) * (NOUT * DOUT) + j * DOUT + d];
    sv += __shfl_xor(sv, 32);
    sv += bias[j * DOUT + d];

    float sq = sv * sv;
#pragma unroll
    for (int o = 16; o; o >>= 1) sq += __shfl_xor(sq, o);

    float scale = (sq / (1.0f + sq)) * rsqrtf(sq + 1e-9f);
    float v = scale * sv;
    if (t < 32) v_out[((size_t)b * NOUT + j) * DOUT + d] = v;
}

extern "C" void kernel_launch(void* const* d_in, const int* in_sizes, int n_in,
                              void* d_out, int out_size, void* d_ws, size_t ws_size,
                              hipStream_t stream) {
    const float* x    = (const float*)d_in[0];
    const float* W    = (const float*)d_in[1];
    const float* bias = (const float*)d_in[2];
    float* out = (float*)d_out;

    const size_t nblog  = (size_t)CB * NIN * NOUT;           // 4,194,304 f
    const size_t nspart = (size_t)CB * NCHUNK * NOUT * DOUT; // 8,388,608 f
    const size_t nv     = (size_t)CB * NOUT * DOUT;          // 65,536 f
    const size_t wbf_bytes  = WELEM * 2;                     // 134,217,728 B
    const size_t rest_bytes = (nblog + nspart + nv) * 4;     // 50,593,792 B
    const bool useBF = ws_size >= wbf_bytes + rest_bytes;

    char* base = (char*)d_ws;
    uint32_t* Wbf = useBF ? (uint32_t*)base : nullptr;
    float* blog  = (float*)(base + (useBF ? wbf_bytes : 0));
    float* spart = blog + nblog;
    float* vbuf  = spart + nspart;

    dim3 grid(512), blk(512);

    caps_pass0<<<grid, blk, 0, stream>>>(x, W, Wbf, spart);
    caps_squash<<<CB * NOUT, 64, 0, stream>>>(spart, bias, vbuf);

    if (useBF) {
        caps_pass<1, 1><<<grid, blk, 0, stream>>>(x, Wbf, vbuf, nullptr, blog, spart);
        caps_squash<<<CB * NOUT, 64, 0, stream>>>(spart, bias, vbuf);
        caps_pass<2, 1><<<grid, blk, 0, stream>>>(x, Wbf, vbuf, blog, nullptr, spart);
    } else {
        caps_pass<1, 0><<<grid, blk, 0, stream>>>(x, W, vbuf, nullptr, blog, spart);
        caps_squash<<<CB * NOUT, 64, 0, stream>>>(spart, bias, vbuf);
        caps_pass<2, 0><<<grid, blk, 0, stream>>>(x, W, vbuf, blog, nullptr, spart);
    }
    caps_squash<<<CB * NOUT, 64, 0, stream>>>(spart, bias, out);
}

// Round 5
// 623.343 us; speedup vs baseline: 3.0592x; 3.0592x over previous
//
#include <hip/hip_runtime.h>
#include <hip/hip_bf16.h>
#include <stdint.h>

// Capsule routing, f32 in/out. B=32, Nin=2048, Din=16, Nout=64, Dout=32, 3 iters.
// Round 5: round-2 register-blocked structure (G=8, 64j x 8dq threads) +
// bf16 W materialized in pass 0 (L3-resident for passes 1-2) + grid 512
// (2 blocks/CU). launch_bounds(512,2) => 128-VGPR cap (the (512,4) in round 4
// capped at 64 VGPR and spilled 1.9GB to scratch). bf16 loads phased per
// k-half to keep live regs <= ~125.

#define CB    32
#define NIN   2048
#define DIN   16
#define NOUT  64
#define DOUT  32
#define CHUNK 16
#define NCHUNK (NIN / CHUNK)     // 128
#define G     8
#define WI    (NOUT * DOUT * DIN)          // 32768 floats per i
#define WELEM ((size_t)NIN * WI)           // 67,108,864 elements

static __device__ __forceinline__ uint32_t pack_bf2(float a, float b) {
    __hip_bfloat162 h = __float22bfloat162_rn(make_float2(a, b));
    uint32_t u; __builtin_memcpy(&u, &h, 4); return u;
}
static __device__ __forceinline__ float bf_lo(uint32_t u) {
    uint32_t v = u << 16; float f; __builtin_memcpy(&f, &v, 4); return f;
}
static __device__ __forceinline__ float bf_hi(uint32_t u) {
    uint32_t v = u & 0xffff0000u; float f; __builtin_memcpy(&f, &v, 4); return f;
}

// ---------------- Pass 0: uniform coupling, f32 W, emits bf16 W copy ----------------
__global__ __launch_bounds__(512, 2) void caps_pass0(
    const float* __restrict__ x, const float* __restrict__ W,
    uint32_t* __restrict__ Wbf, float* __restrict__ s_partial)
{
    const int p     = blockIdx.x;                  // 512 blocks, 2/CU
    const int chunk = (p >> 5) * 8 + (p & 7);      // 4 bg of a chunk share an XCD
    const int bg    = (p & 31) >> 3;
    const int b0    = bg * G;
    const int t     = threadIdx.x;
    const int j     = t >> 3, dq = t & 7;

    __shared__ float sh_x[G * CHUNK * DIN];        // 8KB
    {
        const int bb = t >> 6, rem = t & 63;
        *(float4*)&sh_x[bb * (CHUNK * DIN) + rem * 4] =
            *(const float4*)(x + (size_t)(b0 + bb) * (NIN * DIN)
                               + (size_t)chunk * (CHUNK * DIN) + rem * 4);
    }
    __syncthreads();

    float sacc[G][4];
#pragma unroll
    for (int bb = 0; bb < G; ++bb)
#pragma unroll
        for (int r = 0; r < 4; ++r) sacc[bb][r] = 0.f;

    const size_t thrW = (size_t)j * (DOUT * DIN) + (size_t)(dq * 4) * DIN;

#pragma unroll 1
    for (int ii = 0; ii < CHUNK; ++ii) {
        const int i = chunk * CHUNK + ii;
        const float4* wp = (const float4*)(W + (size_t)i * WI + thrW);
        float4 wf[16];
#pragma unroll
        for (int q = 0; q < 16; ++q) wf[q] = wp[q];

        // emit bf16 W: each i written by exactly one bg
        if (Wbf != nullptr && bg == (ii & 3)) {
            uint32_t* dst = Wbf + ((size_t)i * WI + thrW) / 2;
#pragma unroll
            for (int g8 = 0; g8 < 8; ++g8) {
                uint4 pk;
                pk.x = pack_bf2(wf[2*g8].x,   wf[2*g8].y);
                pk.y = pack_bf2(wf[2*g8].z,   wf[2*g8].w);
                pk.z = pack_bf2(wf[2*g8+1].x, wf[2*g8+1].y);
                pk.w = pack_bf2(wf[2*g8+1].z, wf[2*g8+1].w);
                *(uint4*)(dst + g8 * 4) = pk;
            }
        }

#pragma unroll
        for (int bb = 0; bb < G; ++bb) {
            const float4* xp = (const float4*)&sh_x[bb * (CHUNK * DIN) + ii * DIN];
            const float4 x0 = xp[0], x1 = xp[1], x2 = xp[2], x3 = xp[3];
#pragma unroll
            for (int r = 0; r < 4; ++r) {
                const float4 wA = wf[r*4+0], wB = wf[r*4+1], wC = wf[r*4+2], wD = wf[r*4+3];
                sacc[bb][r] += wA.x*x0.x + wA.y*x0.y + wA.z*x0.z + wA.w*x0.w
                             + wB.x*x1.x + wB.y*x1.y + wB.z*x1.z + wB.w*x1.w
                             + wC.x*x2.x + wC.y*x2.y + wC.z*x2.z + wC.w*x2.w
                             + wD.x*x3.x + wD.y*x3.y + wD.z*x3.z + wD.w*x3.w;
            }
        }
    }

#pragma unroll
    for (int bb = 0; bb < G; ++bb) {
        float4 o;
        o.x = sacc[bb][0] * (1.0f/64.0f); o.y = sacc[bb][1] * (1.0f/64.0f);
        o.z = sacc[bb][2] * (1.0f/64.0f); o.w = sacc[bb][3] * (1.0f/64.0f);
        *(float4*)(s_partial + ((size_t)(b0 + bb) * NCHUNK + chunk) * (NOUT * DOUT) + t * 4) = o;
    }
}

// ---------------- Passes 1-2: routing iterations ----------------
template <int IT, int WBF>
__global__ __launch_bounds__(512, 2) void caps_pass(
    const float* __restrict__ x, const void* __restrict__ Wv,
    const float* __restrict__ v_prev, const float* __restrict__ blog_in,
    float* __restrict__ blog_out, float* __restrict__ s_partial)
{
    const int p     = blockIdx.x;
    const int chunk = (p >> 5) * 8 + (p & 7);
    const int bg    = (p & 31) >> 3;
    const int b0    = bg * G;
    const int t     = threadIdx.x;
    const int j     = t >> 3, dq = t & 7;
    const int w     = t >> 6, l = t & 63;

    __shared__ float    sh_x[G * CHUNK * DIN];      // 8KB
    __shared__ float    sh_bl[2][G * NOUT];         // 4KB (parity double-buffer)
    __shared__ float    sh_red[2][G * 2];
    __shared__ uint32_t sh_vp[G * NOUT * DOUT / 2]; // packed-bf16 v slice, 32KB

    {
        const int bb = t >> 6, rem = t & 63;
        *(float4*)&sh_x[bb * (CHUNK * DIN) + rem * 4] =
            *(const float4*)(x + (size_t)(b0 + bb) * (NIN * DIN)
                               + (size_t)chunk * (CHUNK * DIN) + rem * 4);
    }
    for (int q = t; q < G * NOUT * DOUT / 2; q += 512) {
        const float2 vv = *(const float2*)(v_prev + (size_t)b0 * (NOUT * DOUT) + (size_t)q * 2);
        sh_vp[q] = pack_bf2(vv.x, vv.y);
    }
    __syncthreads();

    float sacc[G][4];
#pragma unroll
    for (int bb = 0; bb < G; ++bb)
#pragma unroll
        for (int r = 0; r < 4; ++r) sacc[bb][r] = 0.f;

    const uint32_t* Wb = (const uint32_t*)Wv;
    const float*    Wf = (const float*)Wv;
    const size_t thrW = (size_t)j * (DOUT * DIN) + (size_t)(dq * 4) * DIN;

#pragma unroll 1
    for (int ii = 0; ii < CHUNK; ++ii) {
        const int i = chunk * CHUNK + ii;

        float uh[G][4];
#pragma unroll
        for (int bb = 0; bb < G; ++bb)
#pragma unroll
            for (int r = 0; r < 4; ++r) uh[bb][r] = 0.f;

        if constexpr (WBF) {
            // row r of this thread's 4 d-rows = dwords [r*8, r*8+8); k-half kh
            // uses dwords r*8 + kh*4 .. +3. Phase the loads per kh to bound
            // live registers (4 loads + 32-float unpack per phase).
            const uint32_t* wrow = Wb + ((size_t)i * WI + thrW) / 2;
#pragma unroll
            for (int kh = 0; kh < 2; ++kh) {
                uint4 wq[4];
#pragma unroll
                for (int r = 0; r < 4; ++r)
                    wq[r] = *(const uint4*)(wrow + r * 8 + kh * 4);
                float wv[4][8];
#pragma unroll
                for (int r = 0; r < 4; ++r) {
                    wv[r][0] = bf_lo(wq[r].x); wv[r][1] = bf_hi(wq[r].x);
                    wv[r][2] = bf_lo(wq[r].y); wv[r][3] = bf_hi(wq[r].y);
                    wv[r][4] = bf_lo(wq[r].z); wv[r][5] = bf_hi(wq[r].z);
                    wv[r][6] = bf_lo(wq[r].w); wv[r][7] = bf_hi(wq[r].w);
                }
#pragma unroll
                for (int bb = 0; bb < G; ++bb) {
                    const float4* xp = (const float4*)&sh_x[bb * (CHUNK * DIN) + ii * DIN + kh * 8];
                    const float4 xA = xp[0], xB = xp[1];
#pragma unroll
                    for (int r = 0; r < 4; ++r) {
                        uh[bb][r] += wv[r][0]*xA.x + wv[r][1]*xA.y + wv[r][2]*xA.z + wv[r][3]*xA.w
                                   + wv[r][4]*xB.x + wv[r][5]*xB.y + wv[r][6]*xB.z + wv[r][7]*xB.w;
                    }
                }
            }
        } else {
            const float4* wp = (const float4*)(Wf + (size_t)i * WI + thrW);
            float4 wf[16];
#pragma unroll
            for (int q = 0; q < 16; ++q) wf[q] = wp[q];
#pragma unroll
            for (int bb = 0; bb < G; ++bb) {
                const float4* xp = (const float4*)&sh_x[bb * (CHUNK * DIN) + ii * DIN];
                const float4 x0 = xp[0], x1 = xp[1], x2 = xp[2], x3 = xp[3];
#pragma unroll
                for (int r = 0; r < 4; ++r) {
                    const float4 wA = wf[r*4+0], wB = wf[r*4+1], wC = wf[r*4+2], wD = wf[r*4+3];
                    uh[bb][r] += wA.x*x0.x + wA.y*x0.y + wA.z*x0.z + wA.w*x0.w
                               + wB.x*x1.x + wB.y*x1.y + wB.z*x1.z + wB.w*x1.w
                               + wC.x*x2.x + wC.y*x2.y + wC.z*x2.z + wC.w*x2.w
                               + wD.x*x3.x + wD.y*x3.y + wD.z*x3.z + wD.w*x3.w;
                }
            }
        }

        const int par = ii & 1;
        // logits: dot over all 32 d via oct butterfly; store to LDS (+ blog I/O)
#pragma unroll
        for (int bb = 0; bb < G; ++bb) {
            const uint2 vp = *(const uint2*)&sh_vp[bb * (NOUT * DOUT / 2) + j * (DOUT / 2) + dq * 2];
            float dlg = uh[bb][0]*bf_lo(vp.x) + uh[bb][1]*bf_hi(vp.x)
                      + uh[bb][2]*bf_lo(vp.y) + uh[bb][3]*bf_hi(vp.y);
            dlg += __shfl_xor(dlg, 1);
            dlg += __shfl_xor(dlg, 2);
            dlg += __shfl_xor(dlg, 4);
            if (IT == 2) dlg += blog_in[((size_t)(b0 + bb) * NIN + i) * NOUT + j];
            if (dq == 0) {
                sh_bl[par][bb * NOUT + j] = dlg;
                if (IT == 1) blog_out[((size_t)(b0 + bb) * NIN + i) * NOUT + j] = dlg;
            }
        }
        __syncthreads();   // logits visible

        // softmax over 64 j: wave w handles local batch w
        {
            const float val = sh_bl[par][w * NOUT + l];
            float m = val;
#pragma unroll
            for (int o = 32; o; o >>= 1) m = fmaxf(m, __shfl_xor(m, o));
            float e = __expf(val - m);
#pragma unroll
            for (int o = 32; o; o >>= 1) e += __shfl_xor(e, o);
            if (l == 0) { sh_red[par][w * 2] = m; sh_red[par][w * 2 + 1] = 1.0f / e; }
        }
        __syncthreads();   // m, 1/sum visible

#pragma unroll
        for (int bb = 0; bb < G; ++bb) {
            const float m   = sh_red[par][bb * 2];
            const float inv = sh_red[par][bb * 2 + 1];
            const float c = __expf(sh_bl[par][bb * NOUT + j] - m) * inv;
#pragma unroll
            for (int r = 0; r < 4; ++r) sacc[bb][r] += c * uh[bb][r];
        }
    }

#pragma unroll
    for (int bb = 0; bb < G; ++bb) {
        float4 o;
        o.x = sacc[bb][0]; o.y = sacc[bb][1]; o.z = sacc[bb][2]; o.w = sacc[bb][3];
        *(float4*)(s_partial + ((size_t)(b0 + bb) * NCHUNK + chunk) * (NOUT * DOUT) + t * 4) = o;
    }
}

// ---------------- Reduce partials, add bias, squash. One wave per (b,j). ----------------
__global__ __launch_bounds__(64) void caps_squash(
    const float* __restrict__ s_partial,  // [B, NCHUNK, NOUT*DOUT]
    const float* __restrict__ bias,       // [NOUT, DOUT]
    float* __restrict__ v_out)            // [B, NOUT, DOUT]
{
    const int bj = blockIdx.x;
    const int b  = bj / NOUT;
    const int j  = bj % NOUT;
    const int t  = threadIdx.x;
    const int d  = t & 31;
    const int h  = t >> 5;

    float sv = 0.f;
    for (int c = h; c < NCHUNK; c += 2)
        sv += s_partial[((size_t)b * NCHUNK + c) * (NOUT * DOUT) + j * DOUT + d];
    sv += __shfl_xor(sv, 32);
    sv += bias[j * DOUT + d];

    float sq = sv * sv;
#pragma unroll
    for (int o = 16; o; o >>= 1) sq += __shfl_xor(sq, o);

    float scale = (sq / (1.0f + sq)) * rsqrtf(sq + 1e-9f);
    float v = scale * sv;
    if (t < 32) v_out[((size_t)b * NOUT + j) * DOUT + d] = v;
}

extern "C" void kernel_launch(void* const* d_in, const int* in_sizes, int n_in,
                              void* d_out, int out_size, void* d_ws, size_t ws_size,
                              hipStream_t stream) {
    const float* x    = (const float*)d_in[0];
    const float* W    = (const float*)d_in[1];
    const float* bias = (const float*)d_in[2];
    float* out = (float*)d_out;

    const size_t nblog  = (size_t)CB * NIN * NOUT;           // 4,194,304 f
    const size_t nspart = (size_t)CB * NCHUNK * NOUT * DOUT; // 8,388,608 f
    const size_t nv     = (size_t)CB * NOUT * DOUT;          // 65,536 f
    const size_t wbf_bytes  = WELEM * 2;                     // 134,217,728 B
    const size_t rest_bytes = (nblog + nspart + nv) * 4;
    const bool useBF = ws_size >= wbf_bytes + rest_bytes;

    char* base = (char*)d_ws;
    uint32_t* Wbf = useBF ? (uint32_t*)base : nullptr;
    float* blog  = (float*)(base + (useBF ? wbf_bytes : 0));
    float* spart = blog + nblog;
    float* vbuf  = spart + nspart;

    dim3 grid(512), blk(512);

    caps_pass0<<<grid, blk, 0, stream>>>(x, W, Wbf, spart);
    caps_squash<<<CB * NOUT, 64, 0, stream>>>(spart, bias, vbuf);

    if (useBF) {
        caps_pass<1, 1><<<grid, blk, 0, stream>>>(x, Wbf, vbuf, nullptr, blog, spart);
        caps_squash<<<CB * NOUT, 64, 0, stream>>>(spart, bias, vbuf);
        caps_pass<2, 1><<<grid, blk, 0, stream>>>(x, Wbf, vbuf, blog, nullptr, spart);
    } else {
        caps_pass<1, 0><<<grid, blk, 0, stream>>>(x, W, vbuf, nullptr, blog, spart);
        caps_squash<<<CB * NOUT, 64, 0, stream>>>(spart, bias, vbuf);
        caps_pass<2, 0><<<grid, blk, 0, stream>>>(x, W, vbuf, blog, nullptr, spart);
    }
    caps_squash<<<CB * NOUT, 64, 0, stream>>>(spart, bias, out);
}

// Round 6
// 462.188 us; speedup vs baseline: 4.1259x; 1.3487x over previous
//
#include <hip/hip_runtime.h>
#include <stdint.h>

// Capsule routing, f32 in/out. B=32, Nin=2048, Din=16, Nout=64, Dout=32, 3 iters.
// Round 6: chunk-level phase split (logits all-i -> 1 barrier -> softmax all -> 1
// barrier -> recompute u_hat & accumulate) so W-load latency is never drained by
// per-i barriers; W transcoded to f16 and consumed via v_dot2_f32_f16.

#define CB    32
#define NIN   2048
#define DIN   16
#define NOUT  64
#define DOUT  32
#define CHUNK 16
#define NCHUNK (NIN / CHUNK)     // 128
#define G     8
#define WI    (NOUT * DOUT * DIN)          // 32768 elements per i
#define WELEM ((size_t)NIN * WI)           // 67,108,864

typedef _Float16 h2 __attribute__((ext_vector_type(2)));

static __device__ __forceinline__ h2 as_h2(uint32_t u) {
    h2 r; __builtin_memcpy(&r, &u, 4); return r;
}
static __device__ __forceinline__ uint32_t pack_h2(float a, float b) {
    h2 r; r.x = (_Float16)a; r.y = (_Float16)b;
    uint32_t u; __builtin_memcpy(&u, &r, 4); return u;
}

// ---------------- W f32 -> f16 transcode (linear streaming) ----------------
__global__ __launch_bounds__(256) void transcode(
    const float* __restrict__ W, uint32_t* __restrict__ Wh)
{
    const size_t stride = (size_t)gridDim.x * 256;
    for (size_t q = (size_t)blockIdx.x * 256 + threadIdx.x; q < WELEM / 8; q += stride) {
        const float4 a = *(const float4*)(W + q * 8);
        const float4 b = *(const float4*)(W + q * 8 + 4);
        uint4 o;
        o.x = pack_h2(a.x, a.y); o.y = pack_h2(a.z, a.w);
        o.z = pack_h2(b.x, b.y); o.w = pack_h2(b.z, b.w);
        *(uint4*)(Wh + q * 4) = o;
    }
}

// uh[4] = W-rows (4 x 16, f16 pairs in wq[8]) dot x (16, h2 pairs in xA/xB)
static __device__ __forceinline__ void uh_f16(const uint4* wq, uint4 xA, uint4 xB, float* uh) {
#pragma unroll
    for (int r = 0; r < 4; ++r) {
        float a = 0.f;
        a = __builtin_amdgcn_fdot2(as_h2(wq[2*r].x),   as_h2(xA.x), a, false);
        a = __builtin_amdgcn_fdot2(as_h2(wq[2*r].y),   as_h2(xA.y), a, false);
        a = __builtin_amdgcn_fdot2(as_h2(wq[2*r].z),   as_h2(xA.z), a, false);
        a = __builtin_amdgcn_fdot2(as_h2(wq[2*r].w),   as_h2(xA.w), a, false);
        a = __builtin_amdgcn_fdot2(as_h2(wq[2*r+1].x), as_h2(xB.x), a, false);
        a = __builtin_amdgcn_fdot2(as_h2(wq[2*r+1].y), as_h2(xB.y), a, false);
        a = __builtin_amdgcn_fdot2(as_h2(wq[2*r+1].z), as_h2(xB.z), a, false);
        a = __builtin_amdgcn_fdot2(as_h2(wq[2*r+1].w), as_h2(xB.w), a, false);
        uh[r] = a;
    }
}

// f32 fallback (only if workspace too small for f16 W; not expected to run)
static __device__ __forceinline__ void uh_f32(const float4* wf, const float4* xs, float* uh) {
#pragma unroll
    for (int r = 0; r < 4; ++r) {
        float a = 0.f;
#pragma unroll
        for (int q = 0; q < 4; ++q) {
            const float4 w = wf[r*4+q], xv = xs[q];
            a += w.x*xv.x + w.y*xv.y + w.z*xv.z + w.w*xv.w;
        }
        uh[r] = a;
    }
}

// ---------------- Routing pass, phase-split ----------------
// 512 thr: j = t>>3 (0..63), dq = t&7 (d0 = dq*4). Block = (i-chunk, batch-group of 8).
// IT=0: phase C only with c = 1/64. IT=1: logits = u.v (store blog). IT=2: += blog_in.
template <int IT, bool F16>
__global__ __launch_bounds__(512, 2) void caps_pass(
    const float* __restrict__ x, const void* __restrict__ Wv,
    const float* __restrict__ v_prev, const float* __restrict__ blog_in,
    float* __restrict__ blog_out, float* __restrict__ s_partial)
{
    const int p     = blockIdx.x;                 // 512 blocks
    const int chunk = (p >> 5) * 8 + (p & 7);     // 4 bg of a chunk share an XCD
    const int bg    = (p & 31) >> 3;
    const int b0    = bg * G;
    const int t     = threadIdx.x;
    const int j     = t >> 3, dq = t & 7;
    const int w     = t >> 6, l = t & 63;

    __shared__ __align__(16) uint32_t sh_xh[F16 ? G * CHUNK * 8 : 8];   // h2-packed x, 4KB
    __shared__ float sh_xf[F16 ? 4 : G * CHUNK * DIN];                  // f32 x (fallback)
    __shared__ float sh_c[G * CHUNK * NOUT];                            // logits -> coupling, 32KB

    // ---- stage x (one float4 per thread: G*CHUNK*DIN = 2048 floats) ----
    {
        const int f4 = t;                  // 0..511
        const int bb = f4 >> 6, rem = f4 & 63;
        const float4 xv = *(const float4*)(x + (size_t)(b0 + bb) * (NIN * DIN)
                                             + (size_t)chunk * (CHUNK * DIN) + rem * 4);
        if constexpr (F16) {
            sh_xh[f4 * 2 + 0] = pack_h2(xv.x, xv.y);
            sh_xh[f4 * 2 + 1] = pack_h2(xv.z, xv.w);
        } else {
            *(float4*)&sh_xf[bb * (CHUNK * DIN) + rem * 4] = xv;
        }
    }

    float4 vr[G];
    if constexpr (IT > 0) {
#pragma unroll
        for (int bb = 0; bb < G; ++bb)
            vr[bb] = *(const float4*)(v_prev + (size_t)(b0 + bb) * (NOUT * DOUT)
                                      + j * DOUT + dq * 4);
    }
    __syncthreads();

    const size_t thrW = (size_t)j * (DOUT * DIN) + (size_t)(dq * 4) * DIN;  // elements

    // ================= PHASE A: logits for all i (no barriers) =================
    if constexpr (IT > 0) {
#pragma unroll 1
        for (int ii = 0; ii < CHUNK; ++ii) {
            const int i = chunk * CHUNK + ii;
            uint4  wq[8];
            float4 wf[16];
            if constexpr (F16) {
                const uint4* wp = (const uint4*)((const uint32_t*)Wv + ((size_t)i * WI + thrW) / 2);
#pragma unroll
                for (int q = 0; q < 8; ++q) wq[q] = wp[q];
            } else {
                const float4* wp = (const float4*)((const float*)Wv + (size_t)i * WI + thrW);
#pragma unroll
                for (int q = 0; q < 16; ++q) wf[q] = wp[q];
            }
#pragma unroll
            for (int bb = 0; bb < G; ++bb) {
                float uh[4];
                if constexpr (F16) {
                    const uint4 xA = *(const uint4*)&sh_xh[(bb * CHUNK + ii) * 8];
                    const uint4 xB = *(const uint4*)&sh_xh[(bb * CHUNK + ii) * 8 + 4];
                    uh_f16(wq, xA, xB, uh);
                } else {
                    uh_f32(wf, (const float4*)&sh_xf[(bb * CHUNK + ii) * DIN], uh);
                }
                float dlg = uh[0]*vr[bb].x + uh[1]*vr[bb].y + uh[2]*vr[bb].z + uh[3]*vr[bb].w;
                dlg += __shfl_xor(dlg, 1);
                dlg += __shfl_xor(dlg, 2);
                dlg += __shfl_xor(dlg, 4);
                if (dq == 0) sh_c[(bb * CHUNK + ii) * NOUT + j] = dlg;
            }
        }
        __syncthreads();

        // ================= PHASE B: softmax for all 128 rows =================
        // wave w owns batch w; lane = j; butterfly leaves the sum in every lane.
        {
            const int b = b0 + w;
#pragma unroll 1
            for (int q = 0; q < CHUNK; ++q) {
                const int i = chunk * CHUNK + q;
                float bl = sh_c[(w * CHUNK + q) * NOUT + l];
                if constexpr (IT == 2) bl += blog_in[((size_t)b * NIN + i) * NOUT + l];
                if constexpr (IT == 1) blog_out[((size_t)b * NIN + i) * NOUT + l] = bl;
                float m = bl;
#pragma unroll
                for (int o = 32; o; o >>= 1) m = fmaxf(m, __shfl_xor(m, o));
                const float e = __expf(bl - m);
                float s = e;
#pragma unroll
                for (int o = 32; o; o >>= 1) s += __shfl_xor(s, o);
                sh_c[(w * CHUNK + q) * NOUT + l] = e / s;
            }
        }
        __syncthreads();
    }

    // ================= PHASE C: recompute u_hat, accumulate c*u_hat =================
    float sacc[G][4];
#pragma unroll
    for (int bb = 0; bb < G; ++bb)
#pragma unroll
        for (int r = 0; r < 4; ++r) sacc[bb][r] = 0.f;

#pragma unroll 1
    for (int ii = 0; ii < CHUNK; ++ii) {
        const int i = chunk * CHUNK + ii;
        uint4  wq[8];
        float4 wf[16];
        if constexpr (F16) {
            const uint4* wp = (const uint4*)((const uint32_t*)Wv + ((size_t)i * WI + thrW) / 2);
#pragma unroll
            for (int q = 0; q < 8; ++q) wq[q] = wp[q];
        } else {
            const float4* wp = (const float4*)((const float*)Wv + (size_t)i * WI + thrW);
#pragma unroll
            for (int q = 0; q < 16; ++q) wf[q] = wp[q];
        }
#pragma unroll
        for (int bb = 0; bb < G; ++bb) {
            float uh[4];
            if constexpr (F16) {
                const uint4 xA = *(const uint4*)&sh_xh[(bb * CHUNK + ii) * 8];
                const uint4 xB = *(const uint4*)&sh_xh[(bb * CHUNK + ii) * 8 + 4];
                uh_f16(wq, xA, xB, uh);
            } else {
                uh_f32(wf, (const float4*)&sh_xf[(bb * CHUNK + ii) * DIN], uh);
            }
            const float c = (IT == 0) ? (1.0f / 64.0f)
                                      : sh_c[(bb * CHUNK + ii) * NOUT + j];
#pragma unroll
            for (int r = 0; r < 4; ++r) sacc[bb][r] += c * uh[r];
        }
    }

    // store partial s: thread's flat (j,d) range = [t*4, t*4+4)
#pragma unroll
    for (int bb = 0; bb < G; ++bb) {
        float4 o;
        o.x = sacc[bb][0]; o.y = sacc[bb][1]; o.z = sacc[bb][2]; o.w = sacc[bb][3];
        *(float4*)(s_partial + ((size_t)(b0 + bb) * NCHUNK + chunk) * (NOUT * DOUT) + t * 4) = o;
    }
}

// ---------------- Reduce partials, add bias, squash. One wave per (b,j). ----------------
__global__ __launch_bounds__(64) void caps_squash(
    const float* __restrict__ s_partial,  // [B, NCHUNK, NOUT*DOUT]
    const float* __restrict__ bias,       // [NOUT, DOUT]
    float* __restrict__ v_out)            // [B, NOUT, DOUT]
{
    const int bj = blockIdx.x;
    const int b  = bj / NOUT;
    const int j  = bj % NOUT;
    const int t  = threadIdx.x;
    const int d  = t & 31;
    const int h  = t >> 5;

    float sv = 0.f;
    for (int c = h; c < NCHUNK; c += 2)
        sv += s_partial[((size_t)b * NCHUNK + c) * (NOUT * DOUT) + j * DOUT + d];
    sv += __shfl_xor(sv, 32);
    sv += bias[j * DOUT + d];

    float sq = sv * sv;
#pragma unroll
    for (int o = 16; o; o >>= 1) sq += __shfl_xor(sq, o);

    float scale = (sq / (1.0f + sq)) * rsqrtf(sq + 1e-9f);
    float v = scale * sv;
    if (t < 32) v_out[((size_t)b * NOUT + j) * DOUT + d] = v;
}

extern "C" void kernel_launch(void* const* d_in, const int* in_sizes, int n_in,
                              void* d_out, int out_size, void* d_ws, size_t ws_size,
                              hipStream_t stream) {
    const float* x    = (const float*)d_in[0];
    const float* W    = (const float*)d_in[1];
    const float* bias = (const float*)d_in[2];
    float* out = (float*)d_out;

    const size_t nblog  = (size_t)CB * NIN * NOUT;           // 4,194,304 f (16MB)
    const size_t nspart = (size_t)CB * NCHUNK * NOUT * DOUT; // 8,388,608 f (33.5MB)
    const size_t nv     = (size_t)CB * NOUT * DOUT;          // 65,536 f
    const size_t wh_bytes   = WELEM * 2;                     // 134MB (f16 W)
    const size_t rest_bytes = (nblog + nspart + nv) * 4;
    const bool useH = ws_size >= wh_bytes + rest_bytes;

    char* base = (char*)d_ws;
    uint32_t* Wh = useH ? (uint32_t*)base : nullptr;
    float* blog  = (float*)(base + (useH ? wh_bytes : 0));
    float* spart = blog + nblog;
    float* vbuf  = spart + nspart;

    dim3 grid(512), blk(512);

    if (useH) {
        transcode<<<2048, 256, 0, stream>>>(W, Wh);
        caps_pass<0, true><<<grid, blk, 0, stream>>>(x, Wh, nullptr, nullptr, nullptr, spart);
        caps_squash<<<CB * NOUT, 64, 0, stream>>>(spart, bias, vbuf);
        caps_pass<1, true><<<grid, blk, 0, stream>>>(x, Wh, vbuf, nullptr, blog, spart);
        caps_squash<<<CB * NOUT, 64, 0, stream>>>(spart, bias, vbuf);
        caps_pass<2, true><<<grid, blk, 0, stream>>>(x, Wh, vbuf, blog, nullptr, spart);
    } else {
        caps_pass<0, false><<<grid, blk, 0, stream>>>(x, W, nullptr, nullptr, nullptr, spart);
        caps_squash<<<CB * NOUT, 64, 0, stream>>>(spart, bias, vbuf);
        caps_pass<1, false><<<grid, blk, 0, stream>>>(x, W, vbuf, nullptr, blog, spart);
        caps_squash<<<CB * NOUT, 64, 0, stream>>>(spart, bias, vbuf);
        caps_pass<2, false><<<grid, blk, 0, stream>>>(x, W, vbuf, blog, nullptr, spart);
    }
    caps_squash<<<CB * NOUT, 64, 0, stream>>>(spart, bias, out);
}